// Round 5
// baseline (432.775 us; speedup 1.0000x reference)
//
#include <hip/hip_runtime.h>
#include <hip/hip_bf16.h>

#define BATCH 2
#define SEQ   2048
#define DIM   2048
#define NHEAD 16
#define HDIM  128

// LDS strides (elements). All multiples of 8 (16B alignment for b128 ops);
// word-spread verified uniform (conflict-free) for every access pattern used.
#define KSTRIDE 136
#define VSTRIDE 72
#define PSTRIDE 72

typedef __bf16 bf16;
typedef __attribute__((ext_vector_type(2))) __bf16 bf16x2;
typedef __attribute__((ext_vector_type(4))) __bf16 bf16x4;
typedef __attribute__((ext_vector_type(8))) __bf16 bf16x8;
typedef __attribute__((ext_vector_type(4))) float f32x4;

__device__ __forceinline__ void load_lds16(const bf16* g, bf16* l) {
    __builtin_amdgcn_global_load_lds((const __attribute__((address_space(1))) void*)g,
                                     (__attribute__((address_space(3))) void*)l, 16, 0, 0);
}

// v_exp_f32: D = 2^S0 (hardware transcendental)
__device__ __forceinline__ float exp2_hw(float x) { return __builtin_amdgcn_exp2f(x); }

// ---------------------------------------------------------------------------
// cvt: fp32 -> bf16 elementwise (x staging)
// ---------------------------------------------------------------------------
__global__ __launch_bounds__(256)
void cvt_bf16(const float* __restrict__ x, bf16* __restrict__ xb, int n4)
{
    const int i = blockIdx.x * 256 + threadIdx.x;
    if (i < n4) {
        const float4 f = ((const float4*)x)[i];
        ((bf16x4*)xb)[i] = (bf16x4){(bf16)f.x, (bf16)f.y, (bf16)f.z, (bf16)f.w};
    }
}

// ---------------------------------------------------------------------------
// transpose+convert: W[K][N] fp32 -> Wt[N][K] bf16. 64x64 LDS tile, padded.
// ---------------------------------------------------------------------------
__global__ __launch_bounds__(256)
void transpose_w(const float* __restrict__ W, bf16* __restrict__ Wt)
{
    __shared__ bf16 T[64][72];
    const int kb = blockIdx.y * 64, nb = blockIdx.x * 64;
    const int r  = threadIdx.x >> 2;          // 0..63
    const int c0 = (threadIdx.x & 3) * 16;    // 0,16,32,48
    #pragma unroll
    for (int i = 0; i < 16; i += 4) {
        const float4 f = *(const float4*)(W + (size_t)(kb + r) * DIM + nb + c0 + i);
        T[r][c0 + i + 0] = (bf16)f.x;
        T[r][c0 + i + 1] = (bf16)f.y;
        T[r][c0 + i + 2] = (bf16)f.z;
        T[r][c0 + i + 3] = (bf16)f.w;
    }
    __syncthreads();
    bf16x8 o0, o1;
    #pragma unroll
    for (int i = 0; i < 8; ++i) { o0[i] = T[c0 + i][r]; o1[i] = T[c0 + 8 + i][r]; }
    *(bf16x8*)(Wt + (size_t)(nb + r) * DIM + kb + c0)     = o0;
    *(bf16x8*)(Wt + (size_t)(nb + r) * DIM + kb + c0 + 8) = o1;
}

// ---------------------------------------------------------------------------
// GEMM (m97 structure): C[M,N] = A[M,K] @ Bt[N,K]^T. A, Bt bf16 row-major.
// ---------------------------------------------------------------------------
template<bool OUT_F32_BIAS>
__global__ __launch_bounds__(256)
void gemm_bt(const bf16* __restrict__ A, const bf16* __restrict__ Bt,
             const float* __restrict__ bias, void* __restrict__ Cptr,
             int M, int N, int K)
{
    __shared__ bf16 As[128 * 32];
    __shared__ bf16 Bs[128 * 32];

    const int tid  = threadIdx.x;
    const int wave = tid >> 6;
    const int lane = tid & 63;
    const int quad = lane >> 4;
    const int l16  = lane & 15;
    const int wr   = (wave >> 1) * 64;
    const int wc   = (wave & 1) * 64;
    const int rowBase = blockIdx.y * 128;
    const int colBase = blockIdx.x * 128;

    const int srow = wave * 16 + (lane >> 2);
    const int scol = (lane & 3) * 8;
    const bf16* aSrc = A  + (size_t)(rowBase + srow) * K + scol;
    const bf16* bSrc = Bt + (size_t)(colBase + srow) * K + scol;

    f32x4 acc[4][4] = {};

    for (int k0 = 0; k0 < K; k0 += 32) {
        #pragma unroll
        for (int p = 0; p < 2; ++p) {
            load_lds16(aSrc + (size_t)p * 64 * K + k0, As + p * 2048 + wave * 512);
            load_lds16(bSrc + (size_t)p * 64 * K + k0, Bs + p * 2048 + wave * 512);
        }
        __syncthreads();

        bf16x8 a[4], b[4];
        #pragma unroll
        for (int i = 0; i < 4; ++i)
            a[i] = *(const bf16x8*)&As[(wr + i * 16 + l16) * 32 + quad * 8];
        #pragma unroll
        for (int j = 0; j < 4; ++j)
            b[j] = *(const bf16x8*)&Bs[(wc + j * 16 + l16) * 32 + quad * 8];
        #pragma unroll
        for (int i = 0; i < 4; ++i)
            #pragma unroll
            for (int j = 0; j < 4; ++j)
                acc[i][j] = __builtin_amdgcn_mfma_f32_16x16x32_bf16(a[i], b[j], acc[i][j], 0, 0, 0);
        __syncthreads();
    }

    #pragma unroll
    for (int i = 0; i < 4; ++i) {
        #pragma unroll
        for (int j = 0; j < 4; ++j) {
            #pragma unroll
            for (int r = 0; r < 4; ++r) {
                const int row = rowBase + wr + i * 16 + quad * 4 + r;
                const int col = colBase + wc + j * 16 + l16;
                const float v = acc[i][j][r];
                if (OUT_F32_BIAS) ((float*)Cptr)[(size_t)row * N + col] = v + bias[col];
                else              ((bf16*)Cptr)[(size_t)row * N + col] = (bf16)v;
            }
        }
    }
}

// ---------------------------------------------------------------------------
// Attention, round 4: S^T-form flash attention.
//   - 2 waves/block, each wave owns 64 q-rows (q-tile 128); 3 blocks/CU.
//   - Q fragments persistent in registers (pre-scaled by 1/sqrt(HD)*log2e),
//     no Q LDS; for 16x16x32 the B-fragment of Q^T == A-fragment regs of Q.
//   - S^T = K·Q^T via MFMA(A=Ks, B=aq): C-layout then gives each lane 4
//     kv-CONTIGUOUS P values per q -> P spills as ds_write_b64, and PV reads
//     P (A-op) and V^T (B-op) as clean b128 fragments.
//   - no-max softmax (scores bounded), per-lane partial denominators.
// ---------------------------------------------------------------------------
__global__ __launch_bounds__(128, 2)
void attn_kernel(const bf16* __restrict__ q, bf16* __restrict__ y)
{
    __shared__ bf16 Ks[64 * KSTRIDE];     // 17408 B  [kv][hd]
    __shared__ bf16 Vt[HDIM * VSTRIDE];   // 18432 B  [hd][kv]
    __shared__ bf16 Ps[128 * PSTRIDE];    // 18432 B  [q][kv]

    const int tid  = threadIdx.x;
    const int wave = tid >> 6;     // 0..1
    const int lane = tid & 63;
    const int quad = lane >> 4;
    const int l16  = lane & 15;

    const int qt = blockIdx.x;
    const int h  = blockIdx.y;
    const int bb = blockIdx.z;

    const bf16* qb = q + (size_t)bb * SEQ * DIM + (size_t)h * HDIM;

    // Q fragments -> registers, pre-scaled so softmax is exp2(s) directly.
    const float qs = 0.12752820031096662f;   // (1/sqrt(128)) * log2(e)
    bf16x8 aq[4][4];
    #pragma unroll
    for (int nt = 0; nt < 4; ++nt) {
        #pragma unroll
        for (int ks = 0; ks < 4; ++ks) {
            const bf16* src = qb + (size_t)(qt * 128 + wave * 64 + nt * 16 + l16) * DIM + ks * 32 + quad * 8;
            bf16x8 v = *(const bf16x8*)src;
            bf16x8 o;
            #pragma unroll
            for (int e = 0; e < 8; ++e) o[e] = (bf16)((float)v[e] * qs);
            aq[nt][ks] = o;
        }
    }

    float lpart[4] = {0.f, 0.f, 0.f, 0.f};
    f32x4 yacc[4][8] = {};

    const int sp = tid & 31;    // kv pair index (kv = 2*sp, 2*sp+1)
    const int ss = tid >> 5;    // hd slice 0..3 (32 wide)

    for (int kt = 0; kt < SEQ / 64; ++kt) {
        __syncthreads();   // prev iteration done reading Ks/Vt

        // stage K tile [64][hd] and V^T [hd][64]; lane owns 2 kv rows x 32 hd,
        // so V^T writes are paired-kv b32 (conflict-free at stride 72).
        {
            const bf16* src0 = qb + (size_t)(kt * 64 + 2 * sp) * DIM + ss * 32;
            bf16x8 v0[4], v1[4];
            #pragma unroll
            for (int c = 0; c < 4; ++c) {
                v0[c] = *(const bf16x8*)(src0 + c * 8);
                v1[c] = *(const bf16x8*)(src0 + DIM + c * 8);
            }
            #pragma unroll
            for (int c = 0; c < 4; ++c) {
                *(bf16x8*)&Ks[(2 * sp + 0) * KSTRIDE + ss * 32 + c * 8] = v0[c];
                *(bf16x8*)&Ks[(2 * sp + 1) * KSTRIDE + ss * 32 + c * 8] = v1[c];
            }
            #pragma unroll
            for (int c = 0; c < 4; ++c)
                #pragma unroll
                for (int e = 0; e < 8; ++e)
                    *(bf16x2*)&Vt[(ss * 32 + c * 8 + e) * VSTRIDE + 2 * sp] = (bf16x2){v0[c][e], v1[c][e]};
        }
        __syncthreads();

        // S^T phase, streamed per 16-kv strip (mt): MFMA(A=Ks-frag, B=aq).
        // C-layout of S^T: kv = mt*16 + quad*4 + r, q = wave*64 + nt*16 + l16.
        #pragma unroll
        for (int mt = 0; mt < 4; ++mt) {
            bf16x8 ak[4];
            #pragma unroll
            for (int ks = 0; ks < 4; ++ks)
                ak[ks] = *(const bf16x8*)&Ks[(mt * 16 + l16) * KSTRIDE + ks * 32 + quad * 8];
            f32x4 s[4] = {};
            #pragma unroll
            for (int ks = 0; ks < 4; ++ks)
                #pragma unroll
                for (int nt = 0; nt < 4; ++nt)
                    s[nt] = __builtin_amdgcn_mfma_f32_16x16x32_bf16(ak[ks], aq[nt][ks], s[nt], 0, 0, 0);
            #pragma unroll
            for (int nt = 0; nt < 4; ++nt) {
                float p0 = exp2_hw(s[nt][0]);
                float p1 = exp2_hw(s[nt][1]);
                float p2 = exp2_hw(s[nt][2]);
                float p3 = exp2_hw(s[nt][3]);
                lpart[nt] += (p0 + p1) + (p2 + p3);
                *(bf16x4*)&Ps[(wave * 64 + nt * 16 + l16) * PSTRIDE + mt * 16 + quad * 4] =
                    (bf16x4){(bf16)p0, (bf16)p1, (bf16)p2, (bf16)p3};
            }
        }

        // PV: Y += P @ V. A = own-wave P rows (in-wave LDS dependency only),
        // B = V^T rows. No extra barrier needed.
        #pragma unroll
        for (int ks2 = 0; ks2 < 2; ++ks2) {
            bf16x8 ap[4];
            #pragma unroll
            for (int i = 0; i < 4; ++i)
                ap[i] = *(const bf16x8*)&Ps[(wave * 64 + i * 16 + l16) * PSTRIDE + ks2 * 32 + quad * 8];
            #pragma unroll
            for (int n = 0; n < 8; ++n) {
                bf16x8 bv = *(const bf16x8*)&Vt[(n * 16 + l16) * VSTRIDE + ks2 * 32 + quad * 8];
                #pragma unroll
                for (int i = 0; i < 4; ++i)
                    yacc[i][n] = __builtin_amdgcn_mfma_f32_16x16x32_bf16(ap[i], bv, yacc[i][n], 0, 0, 0);
            }
        }
    }

    // denominators: lane holds partial over its 16 kv per q = nt*16 + l16;
    // reduce across the 4 quad-lanes sharing each q.
    float lfull[4];
    #pragma unroll
    for (int nt = 0; nt < 4; ++nt) {
        float l = lpart[nt];
        l += __shfl_xor(l, 16);
        l += __shfl_xor(l, 32);
        lfull[nt] = l;
    }

    // epilogue: yacc C-layout row = wave*64 + i*16 + quad*4 + r (q),
    // col = n*16 + l16 (hd). Fetch the divisor for q%16 = quad*4+r from the
    // lane in our quad-group holding l16 == quad*4+r.
    bf16* yb = y + (size_t)bb * SEQ * DIM + (size_t)(qt * 128) * DIM + (size_t)h * HDIM;
    #pragma unroll
    for (int i = 0; i < 4; ++i) {
        #pragma unroll
        for (int r = 0; r < 4; ++r) {
            const float lv  = __shfl(lfull[i], (lane & 48) | (quad * 4 + r));
            const float inv = 1.f / lv;
            const int row = wave * 64 + i * 16 + quad * 4 + r;
            #pragma unroll
            for (int n = 0; n < 8; ++n)
                yb[(size_t)row * DIM + n * 16 + l16] = (bf16)(yacc[i][n][r] * inv);
        }
    }
}

// ---------------------------------------------------------------------------
extern "C" void kernel_launch(void* const* d_in, const int* in_sizes, int n_in,
                              void* d_out, int out_size, void* d_ws, size_t ws_size,
                              hipStream_t stream)
{
    const float* x  = (const float*)d_in[0];
    const float* Wq = (const float*)d_in[1];
    const float* Wo = (const float*)d_in[2];
    const float* bo = (const float*)d_in[3];
    float* out = (float*)d_out;

    const size_t NELEM = (size_t)BATCH * SEQ * DIM;
    bf16* qws = (bf16*)d_ws;
    bf16* xb  = qws + NELEM;        // reused as yws after gemm1
    bf16* yws = xb;
    bf16* Wt  = xb + NELEM;

    const int M = BATCH * SEQ;
    dim3 gg(DIM / 128, M / 128);
    dim3 gt(DIM / 64, DIM / 64);

    cvt_bf16<<<(int)(NELEM / 4 + 255) / 256, 256, 0, stream>>>(x, xb, (int)(NELEM / 4));
    transpose_w<<<gt, 256, 0, stream>>>(Wq, Wt);
    gemm_bt<false><<<gg, 256, 0, stream>>>(xb, Wt, nullptr, qws, M, DIM, DIM);
    transpose_w<<<gt, 256, 0, stream>>>(Wo, Wt);
    attn_kernel<<<dim3(SEQ / 128, NHEAD, BATCH), 128, 0, stream>>>(qws, yws);
    gemm_bt<true><<<gg, 256, 0, stream>>>(yws, Wt, bo, out, M, DIM, DIM);
}

// Round 6
// 320.965 us; speedup vs baseline: 1.3484x; 1.3484x over previous
//
#include <hip/hip_runtime.h>
#include <hip/hip_bf16.h>

#define BATCH 2
#define SEQ   2048
#define DIM   2048
#define NHEAD 16
#define HDIM  128

// LDS strides (elements). Multiples of 8 (16B alignment for b128). Bank
// audit done per access pattern (see comments at each access).
#define KSTRIDE 136
#define VSTRIDE 72
#define PSTRIDE 72

typedef __bf16 bf16;
typedef __attribute__((ext_vector_type(2))) __bf16 bf16x2;
typedef __attribute__((ext_vector_type(4))) __bf16 bf16x4;
typedef __attribute__((ext_vector_type(8))) __bf16 bf16x8;
typedef __attribute__((ext_vector_type(4))) float f32x4;

__device__ __forceinline__ void load_lds16(const bf16* g, bf16* l) {
    __builtin_amdgcn_global_load_lds((const __attribute__((address_space(1))) void*)g,
                                     (__attribute__((address_space(3))) void*)l, 16, 0, 0);
}

// v_exp_f32: D = 2^S0 (hardware transcendental)
__device__ __forceinline__ float exp2_hw(float x) { return __builtin_amdgcn_exp2f(x); }

// ---------------------------------------------------------------------------
// cvt: fp32 -> bf16 elementwise (x staging)
// ---------------------------------------------------------------------------
__global__ __launch_bounds__(256)
void cvt_bf16(const float* __restrict__ x, bf16* __restrict__ xb, int n4)
{
    const int i = blockIdx.x * 256 + threadIdx.x;
    if (i < n4) {
        const float4 f = ((const float4*)x)[i];
        ((bf16x4*)xb)[i] = (bf16x4){(bf16)f.x, (bf16)f.y, (bf16)f.z, (bf16)f.w};
    }
}

// ---------------------------------------------------------------------------
// transpose+convert: W[K][N] fp32 -> Wt[N][K] bf16. 64x64 LDS tile, padded.
// ---------------------------------------------------------------------------
__global__ __launch_bounds__(256)
void transpose_w(const float* __restrict__ W, bf16* __restrict__ Wt)
{
    __shared__ bf16 T[64][72];
    const int kb = blockIdx.y * 64, nb = blockIdx.x * 64;
    const int r  = threadIdx.x >> 2;          // 0..63
    const int c0 = (threadIdx.x & 3) * 16;    // 0,16,32,48
    #pragma unroll
    for (int i = 0; i < 16; i += 4) {
        const float4 f = *(const float4*)(W + (size_t)(kb + r) * DIM + nb + c0 + i);
        T[r][c0 + i + 0] = (bf16)f.x;
        T[r][c0 + i + 1] = (bf16)f.y;
        T[r][c0 + i + 2] = (bf16)f.z;
        T[r][c0 + i + 3] = (bf16)f.w;
    }
    __syncthreads();
    bf16x8 o0, o1;
    #pragma unroll
    for (int i = 0; i < 8; ++i) { o0[i] = T[c0 + i][r]; o1[i] = T[c0 + 8 + i][r]; }
    *(bf16x8*)(Wt + (size_t)(nb + r) * DIM + kb + c0)     = o0;
    *(bf16x8*)(Wt + (size_t)(nb + r) * DIM + kb + c0 + 8) = o1;
}

// ---------------------------------------------------------------------------
// GEMM (m97 structure): C[M,N] = A[M,K] @ Bt[N,K]^T. A, Bt bf16 row-major.
// ---------------------------------------------------------------------------
template<bool OUT_F32_BIAS>
__global__ __launch_bounds__(256)
void gemm_bt(const bf16* __restrict__ A, const bf16* __restrict__ Bt,
             const float* __restrict__ bias, void* __restrict__ Cptr,
             int M, int N, int K)
{
    __shared__ bf16 As[128 * 32];
    __shared__ bf16 Bs[128 * 32];

    const int tid  = threadIdx.x;
    const int wave = tid >> 6;
    const int lane = tid & 63;
    const int quad = lane >> 4;
    const int l16  = lane & 15;
    const int wr   = (wave >> 1) * 64;
    const int wc   = (wave & 1) * 64;
    const int rowBase = blockIdx.y * 128;
    const int colBase = blockIdx.x * 128;

    const int srow = wave * 16 + (lane >> 2);
    const int scol = (lane & 3) * 8;
    const bf16* aSrc = A  + (size_t)(rowBase + srow) * K + scol;
    const bf16* bSrc = Bt + (size_t)(colBase + srow) * K + scol;

    f32x4 acc[4][4] = {};

    for (int k0 = 0; k0 < K; k0 += 32) {
        #pragma unroll
        for (int p = 0; p < 2; ++p) {
            load_lds16(aSrc + (size_t)p * 64 * K + k0, As + p * 2048 + wave * 512);
            load_lds16(bSrc + (size_t)p * 64 * K + k0, Bs + p * 2048 + wave * 512);
        }
        __syncthreads();

        bf16x8 a[4], b[4];
        #pragma unroll
        for (int i = 0; i < 4; ++i)
            a[i] = *(const bf16x8*)&As[(wr + i * 16 + l16) * 32 + quad * 8];
        #pragma unroll
        for (int j = 0; j < 4; ++j)
            b[j] = *(const bf16x8*)&Bs[(wc + j * 16 + l16) * 32 + quad * 8];
        #pragma unroll
        for (int i = 0; i < 4; ++i)
            #pragma unroll
            for (int j = 0; j < 4; ++j)
                acc[i][j] = __builtin_amdgcn_mfma_f32_16x16x32_bf16(a[i], b[j], acc[i][j], 0, 0, 0);
        __syncthreads();
    }

    #pragma unroll
    for (int i = 0; i < 4; ++i) {
        #pragma unroll
        for (int j = 0; j < 4; ++j) {
            #pragma unroll
            for (int r = 0; r < 4; ++r) {
                const int row = rowBase + wr + i * 16 + quad * 4 + r;
                const int col = colBase + wc + j * 16 + l16;
                const float v = acc[i][j][r];
                if (OUT_F32_BIAS) ((float*)Cptr)[(size_t)row * N + col] = v + bias[col];
                else              ((bf16*)Cptr)[(size_t)row * N + col] = (bf16)v;
            }
        }
    }
}

// ---------------------------------------------------------------------------
// Attention, round 6: S^T-form flash attention, 4 waves x 32 q-rows.
//   - Q fragments persistent in registers (32 VGPRs/wave; pre-scaled by
//     1/sqrt(HD)*log2e); yacc[2][8] = 64 regs (AGPR-able). No spill.
//   - S^T = K·Q^T: C-layout gives 4 kv-contiguous P values/lane -> P spilled
//     as ds_write_b64; PV reads P (A-op) and V^T (B-op) as b128 fragments.
//   - Ks staged with round-3's conflict-free mapping; Vt staged from a
//     second load set (lane owns a kv PAIR) -> paired b32 writes, 2-way max.
//   - no-max softmax (scores bounded: |s| <= 128*qs ~ 16), deferred denom.
// ---------------------------------------------------------------------------
__global__ __launch_bounds__(256, 2)
void attn_kernel(const bf16* __restrict__ q, bf16* __restrict__ y)
{
    __shared__ bf16 Ks[64 * KSTRIDE];     // 17408 B  [kv][hd]
    __shared__ bf16 Vt[HDIM * VSTRIDE];   // 18432 B  [hd][kv]
    __shared__ bf16 Ps[128 * PSTRIDE];    // 18432 B  [q][kv]

    const int tid  = threadIdx.x;
    const int wave = tid >> 6;     // 0..3
    const int lane = tid & 63;
    const int quad = lane >> 4;
    const int l16  = lane & 15;

    const int qt = blockIdx.x;
    const int h  = blockIdx.y;
    const int bb = blockIdx.z;

    const bf16* qb = q + (size_t)bb * SEQ * DIM + (size_t)h * HDIM;

    // Q fragments -> registers (wave owns q rows [wave*32, wave*32+32)).
    const float qs = 0.12752820031096662f;   // (1/sqrt(128)) * log2(e)
    bf16x8 aq[2][4];
    #pragma unroll
    for (int nt = 0; nt < 2; ++nt) {
        #pragma unroll
        for (int ks = 0; ks < 4; ++ks) {
            const bf16* src = qb + (size_t)(qt * 128 + wave * 32 + nt * 16 + l16) * DIM + ks * 32 + quad * 8;
            bf16x8 v = *(const bf16x8*)src;
            bf16x8 o;
            #pragma unroll
            for (int e = 0; e < 8; ++e) o[e] = (bf16)((float)v[e] * qs);
            aq[nt][ks] = o;
        }
    }

    float lpart[2] = {0.f, 0.f};
    f32x4 yacc[2][8] = {};

    // Ks staging mapping (conflict-free: bank = 4*(kr+4j) mod 32 uniform)
    const int kr   = tid >> 2;         // kv row 0..63
    const int koff = (tid & 3) * 32;   // hd offset
    // Vt staging mapping (lane owns kv pair {2sp,2sp+1} x 16 hd)
    const int sp = tid & 31;
    const int ss = tid >> 5;           // 0..7, hd slice of 16

    for (int kt = 0; kt < SEQ / 64; ++kt) {
        __syncthreads();   // prev iteration done reading Ks/Vt

        {
            // Ks: lane loads 32 contiguous hd of one kv row, writes 4 b128.
            const bf16* srcK = qb + (size_t)(kt * 64 + kr) * DIM + koff;
            bf16x8 k0 = *(const bf16x8*)(srcK + 0);
            bf16x8 k1 = *(const bf16x8*)(srcK + 8);
            bf16x8 k2 = *(const bf16x8*)(srcK + 16);
            bf16x8 k3 = *(const bf16x8*)(srcK + 24);
            *(bf16x8*)&Ks[kr * KSTRIDE + koff + 0]  = k0;
            *(bf16x8*)&Ks[kr * KSTRIDE + koff + 8]  = k1;
            *(bf16x8*)&Ks[kr * KSTRIDE + koff + 16] = k2;
            *(bf16x8*)&Ks[kr * KSTRIDE + koff + 24] = k3;
            // Vt: second load set; paired-kv b32 writes (2-way max = free).
            const bf16* srcV = qb + (size_t)(kt * 64 + 2 * sp) * DIM + ss * 16;
            bf16x8 v0[2], v1[2];
            v0[0] = *(const bf16x8*)(srcV + 0);
            v0[1] = *(const bf16x8*)(srcV + 8);
            v1[0] = *(const bf16x8*)(srcV + DIM + 0);
            v1[1] = *(const bf16x8*)(srcV + DIM + 8);
            #pragma unroll
            for (int c = 0; c < 2; ++c)
                #pragma unroll
                for (int e = 0; e < 8; ++e)
                    *(bf16x2*)&Vt[(ss * 16 + c * 8 + e) * VSTRIDE + 2 * sp] = (bf16x2){v0[c][e], v1[c][e]};
        }
        __syncthreads();

        // S^T phase per 16-kv strip (mt): MFMA(A=Ks-frag, B=aq).
        // C-layout of S^T: kv = mt*16 + quad*4 + r, q = wave*32 + nt*16 + l16.
        #pragma unroll
        for (int mt = 0; mt < 4; ++mt) {
            bf16x8 ak[4];
            #pragma unroll
            for (int ks = 0; ks < 4; ++ks)
                ak[ks] = *(const bf16x8*)&Ks[(mt * 16 + l16) * KSTRIDE + ks * 32 + quad * 8];
            f32x4 s[2] = {};
            #pragma unroll
            for (int ks = 0; ks < 4; ++ks)
                #pragma unroll
                for (int nt = 0; nt < 2; ++nt)
                    s[nt] = __builtin_amdgcn_mfma_f32_16x16x32_bf16(ak[ks], aq[nt][ks], s[nt], 0, 0, 0);
            #pragma unroll
            for (int nt = 0; nt < 2; ++nt) {
                float p0 = exp2_hw(s[nt][0]);
                float p1 = exp2_hw(s[nt][1]);
                float p2 = exp2_hw(s[nt][2]);
                float p3 = exp2_hw(s[nt][3]);
                lpart[nt] += (p0 + p1) + (p2 + p3);
                *(bf16x4*)&Ps[(wave * 32 + nt * 16 + l16) * PSTRIDE + mt * 16 + quad * 4] =
                    (bf16x4){(bf16)p0, (bf16)p1, (bf16)p2, (bf16)p3};
            }
        }

        // PV: Y += P @ V. A = own-wave P rows (in-wave LDS dep only), B = V^T.
        #pragma unroll
        for (int ks2 = 0; ks2 < 2; ++ks2) {
            bf16x8 ap[2];
            #pragma unroll
            for (int i = 0; i < 2; ++i)
                ap[i] = *(const bf16x8*)&Ps[(wave * 32 + i * 16 + l16) * PSTRIDE + ks2 * 32 + quad * 8];
            #pragma unroll
            for (int n = 0; n < 8; ++n) {
                bf16x8 bv = *(const bf16x8*)&Vt[(n * 16 + l16) * VSTRIDE + ks2 * 32 + quad * 8];
                #pragma unroll
                for (int i = 0; i < 2; ++i)
                    yacc[i][n] = __builtin_amdgcn_mfma_f32_16x16x32_bf16(ap[i], bv, yacc[i][n], 0, 0, 0);
            }
        }
    }

    // denominators: lane holds partial over its 16 kv per q = nt*16 + l16;
    // reduce across the 4 quad-lanes sharing each q.
    float lfull[2];
    #pragma unroll
    for (int nt = 0; nt < 2; ++nt) {
        float l = lpart[nt];
        l += __shfl_xor(l, 16);
        l += __shfl_xor(l, 32);
        lfull[nt] = l;
    }

    // epilogue: yacc C-layout row = wave*32 + i*16 + quad*4 + r (q),
    // col = n*16 + l16 (hd). Divisor for q%16 = quad*4+r comes from the lane
    // in our 16-group with l16 == quad*4+r.
    bf16* yb = y + (size_t)bb * SEQ * DIM + (size_t)(qt * 128) * DIM + (size_t)h * HDIM;
    #pragma unroll
    for (int i = 0; i < 2; ++i) {
        #pragma unroll
        for (int r = 0; r < 4; ++r) {
            const float lv  = __shfl(lfull[i], (lane & 48) | (quad * 4 + r));
            const float inv = 1.f / lv;
            const int row = wave * 32 + i * 16 + quad * 4 + r;
            #pragma unroll
            for (int n = 0; n < 8; ++n)
                yb[(size_t)row * DIM + n * 16 + l16] = (bf16)(yacc[i][n][r] * inv);
        }
    }
}

// ---------------------------------------------------------------------------
extern "C" void kernel_launch(void* const* d_in, const int* in_sizes, int n_in,
                              void* d_out, int out_size, void* d_ws, size_t ws_size,
                              hipStream_t stream)
{
    const float* x  = (const float*)d_in[0];
    const float* Wq = (const float*)d_in[1];
    const float* Wo = (const float*)d_in[2];
    const float* bo = (const float*)d_in[3];
    float* out = (float*)d_out;

    const size_t NELEM = (size_t)BATCH * SEQ * DIM;
    bf16* qws = (bf16*)d_ws;
    bf16* xb  = qws + NELEM;        // reused as yws after gemm1
    bf16* yws = xb;
    bf16* Wt  = xb + NELEM;

    const int M = BATCH * SEQ;
    dim3 gg(DIM / 128, M / 128);
    dim3 gt(DIM / 64, DIM / 64);

    cvt_bf16<<<(int)(NELEM / 4 + 255) / 256, 256, 0, stream>>>(x, xb, (int)(NELEM / 4));
    transpose_w<<<gt, 256, 0, stream>>>(Wq, Wt);
    gemm_bt<false><<<gg, 256, 0, stream>>>(xb, Wt, nullptr, qws, M, DIM, DIM);
    transpose_w<<<gt, 256, 0, stream>>>(Wo, Wt);
    attn_kernel<<<dim3(SEQ / 128, NHEAD, BATCH), 256, 0, stream>>>(qws, yws);
    gemm_bt<true><<<gg, 256, 0, stream>>>(yws, Wt, bo, out, M, DIM, DIM);
}

// Round 7
// 282.203 us; speedup vs baseline: 1.5336x; 1.1374x over previous
//
#include <hip/hip_runtime.h>
#include <hip/hip_bf16.h>

#define BATCH 2
#define SEQ   2048
#define DIM   2048
#define NHEAD 16
#define HDIM  128

// LDS strides (elements). Multiples of 8 (16B alignment for b128); bank
// audits in comments at each access site.
#define KSTRIDE 136
#define VSTRIDE 72
#define PSTRIDE 72

typedef __bf16 bf16;
typedef __attribute__((ext_vector_type(2))) __bf16 bf16x2;
typedef __attribute__((ext_vector_type(4))) __bf16 bf16x4;
typedef __attribute__((ext_vector_type(8))) __bf16 bf16x8;
typedef __attribute__((ext_vector_type(4))) float f32x4;

__device__ __forceinline__ void load_lds16(const bf16* g, bf16* l) {
    __builtin_amdgcn_global_load_lds((const __attribute__((address_space(1))) void*)g,
                                     (__attribute__((address_space(3))) void*)l, 16, 0, 0);
}

// v_exp_f32: D = 2^S0 (hardware transcendental)
__device__ __forceinline__ float exp2_hw(float x) { return __builtin_amdgcn_exp2f(x); }

// ---------------------------------------------------------------------------
// cvt: fp32 -> bf16 elementwise (x staging)
// ---------------------------------------------------------------------------
__global__ __launch_bounds__(256)
void cvt_bf16(const float* __restrict__ x, bf16* __restrict__ xb, int n4)
{
    const int i = blockIdx.x * 256 + threadIdx.x;
    if (i < n4) {
        const float4 f = ((const float4*)x)[i];
        ((bf16x4*)xb)[i] = (bf16x4){(bf16)f.x, (bf16)f.y, (bf16)f.z, (bf16)f.w};
    }
}

// ---------------------------------------------------------------------------
// transpose+convert: W[K][N] fp32 -> Wt[N][K] bf16. 64x64 LDS tile, padded.
// ---------------------------------------------------------------------------
__global__ __launch_bounds__(256)
void transpose_w(const float* __restrict__ W, bf16* __restrict__ Wt)
{
    __shared__ bf16 T[64][72];
    const int kb = blockIdx.y * 64, nb = blockIdx.x * 64;
    const int r  = threadIdx.x >> 2;          // 0..63
    const int c0 = (threadIdx.x & 3) * 16;    // 0,16,32,48
    #pragma unroll
    for (int i = 0; i < 16; i += 4) {
        const float4 f = *(const float4*)(W + (size_t)(kb + r) * DIM + nb + c0 + i);
        T[r][c0 + i + 0] = (bf16)f.x;
        T[r][c0 + i + 1] = (bf16)f.y;
        T[r][c0 + i + 2] = (bf16)f.z;
        T[r][c0 + i + 3] = (bf16)f.w;
    }
    __syncthreads();
    bf16x8 o0, o1;
    #pragma unroll
    for (int i = 0; i < 8; ++i) { o0[i] = T[c0 + i][r]; o1[i] = T[c0 + 8 + i][r]; }
    *(bf16x8*)(Wt + (size_t)(nb + r) * DIM + kb + c0)     = o0;
    *(bf16x8*)(Wt + (size_t)(nb + r) * DIM + kb + c0 + 8) = o1;
}

// ---------------------------------------------------------------------------
// GEMM: C[M,N] = A[M,K] @ Bt[N,K]^T, bf16 in. BK=64 (two [128][32] half
// buffers keep the m97 bank layout), halving barrier count vs BK=32.
// 128x128 tile, 4 waves 2x2, 4x4 MFMA accs, global_load_lds width=16.
// ---------------------------------------------------------------------------
template<bool OUT_F32_BIAS>
__global__ __launch_bounds__(256)
void gemm_bt(const bf16* __restrict__ A, const bf16* __restrict__ Bt,
             const float* __restrict__ bias, void* __restrict__ Cptr,
             int M, int N, int K)
{
    __shared__ bf16 As[2][128 * 32];   // [k-half][row][32]
    __shared__ bf16 Bs[2][128 * 32];

    const int tid  = threadIdx.x;
    const int wave = tid >> 6;
    const int lane = tid & 63;
    const int quad = lane >> 4;
    const int l16  = lane & 15;
    const int wr   = (wave >> 1) * 64;
    const int wc   = (wave & 1) * 64;
    const int rowBase = blockIdx.y * 128;
    const int colBase = blockIdx.x * 128;

    // staging: issue (rh, kh): wave covers rows rh*64 + wave*16 + (lane>>2),
    // col kh*32 + (lane&3)*8. LDS dest = half-buffer kh, wave-uniform base
    // (rh*64 + wave*16)*32; HW adds lane*16B which matches [row][32] order.
    const int srow = lane >> 2;
    const int scol = (lane & 3) * 8;
    const bf16* aBase = A  + (size_t)(rowBase + wave * 16 + srow) * K + scol;
    const bf16* bBase = Bt + (size_t)(colBase + wave * 16 + srow) * K + scol;

    f32x4 acc[4][4] = {};

    for (int k0 = 0; k0 < K; k0 += 64) {
        #pragma unroll
        for (int rh = 0; rh < 2; ++rh) {
            #pragma unroll
            for (int kh = 0; kh < 2; ++kh) {
                load_lds16(aBase + (size_t)rh * 64 * K + k0 + kh * 32,
                           (bf16*)As[kh] + (rh * 64 + wave * 16) * 32);
                load_lds16(bBase + (size_t)rh * 64 * K + k0 + kh * 32,
                           (bf16*)Bs[kh] + (rh * 64 + wave * 16) * 32);
            }
        }
        __syncthreads();

        #pragma unroll
        for (int ks = 0; ks < 2; ++ks) {
            bf16x8 a[4], b[4];
            #pragma unroll
            for (int i = 0; i < 4; ++i)
                a[i] = *(const bf16x8*)&As[ks][(wr + i * 16 + l16) * 32 + quad * 8];
            #pragma unroll
            for (int j = 0; j < 4; ++j)
                b[j] = *(const bf16x8*)&Bs[ks][(wc + j * 16 + l16) * 32 + quad * 8];
            #pragma unroll
            for (int i = 0; i < 4; ++i)
                #pragma unroll
                for (int j = 0; j < 4; ++j)
                    acc[i][j] = __builtin_amdgcn_mfma_f32_16x16x32_bf16(a[i], b[j], acc[i][j], 0, 0, 0);
        }
        __syncthreads();
    }

    #pragma unroll
    for (int i = 0; i < 4; ++i) {
        #pragma unroll
        for (int j = 0; j < 4; ++j) {
            #pragma unroll
            for (int r = 0; r < 4; ++r) {
                const int row = rowBase + wr + i * 16 + quad * 4 + r;
                const int col = colBase + wc + j * 16 + l16;
                const float v = acc[i][j][r];
                if (OUT_F32_BIAS) ((float*)Cptr)[(size_t)row * N + col] = v + bias[col];
                else              ((bf16*)Cptr)[(size_t)row * N + col] = (bf16)v;
            }
        }
    }
}

// ---------------------------------------------------------------------------
// Attention, round 7: round-6 S^T-form + register-prefetch pipeline.
// Next K/V tile is loaded into VGPRs during the compute phase, so global
// latency no longer sits between the two barriers (which exposed it to all
// 8 resident waves). Everything else identical to the passing round-6 kernel.
// ---------------------------------------------------------------------------
__global__ __launch_bounds__(256, 2)
void attn_kernel(const bf16* __restrict__ q, bf16* __restrict__ y)
{
    __shared__ bf16 Ks[64 * KSTRIDE];     // 17408 B  [kv][hd]
    __shared__ bf16 Vt[HDIM * VSTRIDE];   // 18432 B  [hd][kv]
    __shared__ bf16 Ps[128 * PSTRIDE];    // 18432 B  [q][kv]

    const int tid  = threadIdx.x;
    const int wave = tid >> 6;     // 0..3
    const int lane = tid & 63;
    const int quad = lane >> 4;
    const int l16  = lane & 15;

    const int qt = blockIdx.x;
    const int h  = blockIdx.y;
    const int bb = blockIdx.z;

    const bf16* qb = q + (size_t)bb * SEQ * DIM + (size_t)h * HDIM;

    // Q fragments -> registers (wave owns q rows [wave*32, wave*32+32)).
    const float qs = 0.12752820031096662f;   // (1/sqrt(128)) * log2(e)
    bf16x8 aq[2][4];
    #pragma unroll
    for (int nt = 0; nt < 2; ++nt) {
        #pragma unroll
        for (int ks = 0; ks < 4; ++ks) {
            const bf16* src = qb + (size_t)(qt * 128 + wave * 32 + nt * 16 + l16) * DIM + ks * 32 + quad * 8;
            bf16x8 v = *(const bf16x8*)src;
            bf16x8 o;
            #pragma unroll
            for (int e = 0; e < 8; ++e) o[e] = (bf16)((float)v[e] * qs);
            aq[nt][ks] = o;
        }
    }

    float lpart[2] = {0.f, 0.f};
    f32x4 yacc[2][8] = {};

    // staging index maps (both conflict-free, see round-6 audit)
    const int kr   = tid >> 2;         // kv row 0..63 (Ks path)
    const int koff = (tid & 3) * 32;
    const int sp   = tid & 31;         // kv pair (Vt path)
    const int ss   = tid >> 5;         // hd slice of 16

    const bf16* srcK = qb + (size_t)kr * DIM + koff;
    const bf16* srcV = qb + (size_t)(2 * sp) * DIM + ss * 16;

    // prologue: prefetch tile 0 into registers
    bf16x8 kreg[4], va[2], vb[2];
    #pragma unroll
    for (int c = 0; c < 4; ++c) kreg[c] = *(const bf16x8*)(srcK + c * 8);
    va[0] = *(const bf16x8*)(srcV + 0);
    va[1] = *(const bf16x8*)(srcV + 8);
    vb[0] = *(const bf16x8*)(srcV + DIM + 0);
    vb[1] = *(const bf16x8*)(srcV + DIM + 8);

    for (int kt = 0; kt < SEQ / 64; ++kt) {
        __syncthreads();   // prev iteration done reading Ks/Vt

        // commit prefetched tile to LDS
        #pragma unroll
        for (int c = 0; c < 4; ++c)
            *(bf16x8*)&Ks[kr * KSTRIDE + koff + c * 8] = kreg[c];
        #pragma unroll
        for (int c = 0; c < 2; ++c)
            #pragma unroll
            for (int e = 0; e < 8; ++e)
                *(bf16x2*)&Vt[(ss * 16 + c * 8 + e) * VSTRIDE + 2 * sp] = (bf16x2){va[c][e], vb[c][e]};

        // prefetch NEXT tile (overlaps the whole compute phase below)
        if (kt + 1 < SEQ / 64) {
            const bf16* nK = srcK + (size_t)(kt + 1) * 64 * DIM;
            const bf16* nV = srcV + (size_t)(kt + 1) * 64 * DIM;
            #pragma unroll
            for (int c = 0; c < 4; ++c) kreg[c] = *(const bf16x8*)(nK + c * 8);
            va[0] = *(const bf16x8*)(nV + 0);
            va[1] = *(const bf16x8*)(nV + 8);
            vb[0] = *(const bf16x8*)(nV + DIM + 0);
            vb[1] = *(const bf16x8*)(nV + DIM + 8);
        }
        __syncthreads();

        // S^T phase per 16-kv strip (mt): MFMA(A=Ks-frag, B=aq).
        // C-layout of S^T: kv = mt*16 + quad*4 + r, q = wave*32 + nt*16 + l16.
        #pragma unroll
        for (int mt = 0; mt < 4; ++mt) {
            bf16x8 ak[4];
            #pragma unroll
            for (int ks = 0; ks < 4; ++ks)
                ak[ks] = *(const bf16x8*)&Ks[(mt * 16 + l16) * KSTRIDE + ks * 32 + quad * 8];
            f32x4 s[2] = {};
            #pragma unroll
            for (int ks = 0; ks < 4; ++ks)
                #pragma unroll
                for (int nt = 0; nt < 2; ++nt)
                    s[nt] = __builtin_amdgcn_mfma_f32_16x16x32_bf16(ak[ks], aq[nt][ks], s[nt], 0, 0, 0);
            #pragma unroll
            for (int nt = 0; nt < 2; ++nt) {
                float p0 = exp2_hw(s[nt][0]);
                float p1 = exp2_hw(s[nt][1]);
                float p2 = exp2_hw(s[nt][2]);
                float p3 = exp2_hw(s[nt][3]);
                lpart[nt] += (p0 + p1) + (p2 + p3);
                *(bf16x4*)&Ps[(wave * 32 + nt * 16 + l16) * PSTRIDE + mt * 16 + quad * 4] =
                    (bf16x4){(bf16)p0, (bf16)p1, (bf16)p2, (bf16)p3};
            }
        }

        // PV: Y += P @ V. A = own-wave P rows (in-wave LDS dep only), B = V^T.
        #pragma unroll
        for (int ks2 = 0; ks2 < 2; ++ks2) {
            bf16x8 ap[2];
            #pragma unroll
            for (int i = 0; i < 2; ++i)
                ap[i] = *(const bf16x8*)&Ps[(wave * 32 + i * 16 + l16) * PSTRIDE + ks2 * 32 + quad * 8];
            #pragma unroll
            for (int n = 0; n < 8; ++n) {
                bf16x8 bv = *(const bf16x8*)&Vt[(n * 16 + l16) * VSTRIDE + ks2 * 32 + quad * 8];
                #pragma unroll
                for (int i = 0; i < 2; ++i)
                    yacc[i][n] = __builtin_amdgcn_mfma_f32_16x16x32_bf16(ap[i], bv, yacc[i][n], 0, 0, 0);
            }
        }
    }

    // denominators: lane holds partial over its 16 kv per q = nt*16 + l16;
    // reduce across the 4 quad-lanes sharing each q.
    float lfull[2];
    #pragma unroll
    for (int nt = 0; nt < 2; ++nt) {
        float l = lpart[nt];
        l += __shfl_xor(l, 16);
        l += __shfl_xor(l, 32);
        lfull[nt] = l;
    }

    // epilogue: yacc C-layout row = wave*32 + i*16 + quad*4 + r (q),
    // col = n*16 + l16 (hd).
    bf16* yb = y + (size_t)bb * SEQ * DIM + (size_t)(qt * 128) * DIM + (size_t)h * HDIM;
    #pragma unroll
    for (int i = 0; i < 2; ++i) {
        #pragma unroll
        for (int r = 0; r < 4; ++r) {
            const float lv  = __shfl(lfull[i], (lane & 48) | (quad * 4 + r));
            const float inv = 1.f / lv;
            const int row = wave * 32 + i * 16 + quad * 4 + r;
            #pragma unroll
            for (int n = 0; n < 8; ++n)
                yb[(size_t)row * DIM + n * 16 + l16] = (bf16)(yacc[i][n][r] * inv);
        }
    }
}

// ---------------------------------------------------------------------------
extern "C" void kernel_launch(void* const* d_in, const int* in_sizes, int n_in,
                              void* d_out, int out_size, void* d_ws, size_t ws_size,
                              hipStream_t stream)
{
    const float* x  = (const float*)d_in[0];
    const float* Wq = (const float*)d_in[1];
    const float* Wo = (const float*)d_in[2];
    const float* bo = (const float*)d_in[3];
    float* out = (float*)d_out;

    const size_t NELEM = (size_t)BATCH * SEQ * DIM;
    bf16* qws = (bf16*)d_ws;
    bf16* xb  = qws + NELEM;        // reused as yws after gemm1
    bf16* yws = xb;
    bf16* Wt  = xb + NELEM;

    const int M = BATCH * SEQ;
    dim3 gg(DIM / 128, M / 128);
    dim3 gt(DIM / 64, DIM / 64);

    cvt_bf16<<<(int)(NELEM / 4 + 255) / 256, 256, 0, stream>>>(x, xb, (int)(NELEM / 4));
    transpose_w<<<gt, 256, 0, stream>>>(Wq, Wt);
    gemm_bt<false><<<gg, 256, 0, stream>>>(xb, Wt, nullptr, qws, M, DIM, DIM);
    transpose_w<<<gt, 256, 0, stream>>>(Wo, Wt);
    attn_kernel<<<dim3(SEQ / 128, NHEAD, BATCH), 256, 0, stream>>>(qws, yws);
    gemm_bt<true><<<gg, 256, 0, stream>>>(yws, Wt, bo, out, M, DIM, DIM);
}